// Round 2
// baseline (1342.480 us; speedup 1.0000x reference)
//
#include <hip/hip_runtime.h>
#include <stdint.h>

// VQEmbedding: z[B,2D] fp32, W_a/W_v [K,D] fp32.
// out0 = z_q_st [B,2D], out1 = z_q [B,2D], out2 = scores [B,2K].
//
// Round 2 (resubmit): split-bf16 MFMA GEMM.
//   scores = z*W^T computed as hi*hi + hi*lo + lo*hi in mfma_f32_16x16x32_bf16
//   (fp32 accum). Error ~5e-9 abs on sigma=1.6e-3 scores.
//   Argmax robustness: per-row global top-2 via two-slot atomicMax protocol,
//   then exact-fp32 rescore of both candidates in fixup_kernel.
// MFMA floor = 3*137.4 GF / 2495 TF ~= 165us; target ~350-500us total.

namespace {
constexpr int D     = 512;
constexpr int TWO_D = 1024;
constexpr int K     = 8192;   // codebook entries per half
constexpr int B     = 8192;   // batch
constexpr int BM = 128, BN = 128, BK = 32;   // BK in fp32 k-elems
constexpr int NCHUNK = D / BK;               // 16
}

typedef __attribute__((ext_vector_type(8))) short short8;
typedef __attribute__((ext_vector_type(4))) float f32x4;

// Monotonic float->uint key: orders like fp32 compare (handles sign).
__device__ __forceinline__ unsigned int score_key(float s) {
    unsigned int u = __float_as_uint(s);
    return (u & 0x80000000u) ? ~u : (u | 0x80000000u);
}

__device__ __forceinline__ unsigned long long shfl_xor_u64(unsigned long long v, int m) {
    unsigned int hi = (unsigned int)(v >> 32), lo = (unsigned int)v;
    hi = __shfl_xor(hi, m, 64);
    lo = __shfl_xor(lo, m, 64);
    return ((unsigned long long)hi << 32) | lo;
}

// Split (x0,x1) into hi (truncated bf16, packed pair) and lo (RNE bf16 of
// remainder, packed pair). Truncated hi keeps the unpack for lo at 1 AND.
__device__ __forceinline__ void cvt_pair(float x0, float x1, unsigned &hiw, unsigned &low) {
    unsigned u0 = __float_as_uint(x0), u1 = __float_as_uint(x1);
    hiw = (u0 >> 16) | (u1 & 0xFFFF0000u);
    float l0 = x0 - __uint_as_float(u0 & 0xFFFF0000u);
    float l1 = x1 - __uint_as_float(u1 & 0xFFFF0000u);
    asm("v_cvt_pk_bf16_f32 %0, %1, %2" : "=v"(low) : "v"(l0), "v"(l1));
}

// 8 consecutive k-elems (two float4) -> one 16B hi chunk + one 16B lo chunk.
__device__ __forceinline__ void cvt8(float4 a, float4 b, uint4 &h, uint4 &l) {
    cvt_pair(a.x, a.y, h.x, l.x);
    cvt_pair(a.z, a.w, h.y, l.y);
    cvt_pair(b.x, b.y, h.z, l.z);
    cvt_pair(b.z, b.w, h.w, l.w);
}

__global__ void init_ws_kernel(unsigned long long* __restrict__ ws) {
    int i = blockIdx.x * blockDim.x + threadIdx.x;
    if (i < 4 * B) ws[i] = 0ull;   // slot1[2B] + slot2[2B]
}

__global__ __launch_bounds__(256, 2) void gemm_argmax_kernel(
    const float* __restrict__ z,      // [B, 2D]
    const float* __restrict__ Wa,     // [K, D]
    const float* __restrict__ Wv,     // [K, D]
    float* __restrict__ scores,       // [B, 2K]
    unsigned long long* __restrict__ slot1,   // [2][B]
    unsigned long long* __restrict__ slot2)   // [2][B]
{
    // LDS: Ahi | Alo | Bhi | Blo, each [128 rows][32 bf16] = 8 KB, 32 KB total.
    // 16B-chunk XOR swizzle (chunk ^= row&3) -> b128 frag reads at 8 words/bank floor.
    __shared__ uint4 smem4[2048];
    char* smem = (char*)smem4;
    constexpr int AHI = 0, ALO = 8192, BHI = 16384, BLO = 24576;

    const int h = blockIdx.z;
    const float* __restrict__ W = h ? Wv : Wa;

    // bijective XCD chunked swizzle over the 64x64 tile grid (4096 % 8 == 0)
    int id = blockIdx.y * 64 + blockIdx.x;
    id = (id & 7) * 512 + (id >> 3);
    const int rowBase = (id >> 6) * BM;
    const int colBase = (id & 63) * BN;

    const int tid  = threadIdx.x;
    const int lane = tid & 63;
    const int wv   = tid >> 6;          // wave 0..3, arranged 2x2
    const int wr   = wv >> 1, wc = wv & 1;
    const int fr   = lane & 15, fq = lane >> 4;

    // staging map: thread -> (row sr, k-half sk)
    const int sr = tid >> 1;            // 0..127
    const int sk = (tid & 1) << 4;      // 0 / 16 (fp32 elems)
    const int c0 = (tid & 1) << 1;      // first 16B chunk idx (0 / 2)
    const int swzr = sr & 3;
    const int wb0 = sr * 64 + (((c0 + 0) ^ swzr) << 4);
    const int wb1 = sr * 64 + (((c0 + 1) ^ swzr) << 4);

    const float* zp = z + (size_t)(rowBase + sr) * TWO_D + h * D + sk;
    const float* wp = W + (size_t)(colBase + sr) * D + sk;

    // fragment read offsets (swz depends only on fr&3 since rows are base+fr)
    const int swzc = (fq ^ (fr & 3)) << 4;
    const int aOff = (wr * 64 + fr) * 64 + swzc;
    const int bOff = (wc * 64 + fr) * 64 + swzc;

    f32x4 acc[4][4];
#pragma unroll
    for (int m = 0; m < 4; ++m)
#pragma unroll
        for (int n = 0; n < 4; ++n) acc[m][n] = (f32x4){0.f, 0.f, 0.f, 0.f};

    float4 a0, a1, a2, a3, b0, b1, b2, b3;
    a0 = *(const float4*)(zp + 0);  a1 = *(const float4*)(zp + 4);
    a2 = *(const float4*)(zp + 8);  a3 = *(const float4*)(zp + 12);
    b0 = *(const float4*)(wp + 0);  b1 = *(const float4*)(wp + 4);
    b2 = *(const float4*)(wp + 8);  b3 = *(const float4*)(wp + 12);

    for (int kc = 0; kc < NCHUNK; ++kc) {
        uint4 ah0, ah1, al0, al1, bh0, bh1, bl0, bl1;
        cvt8(a0, a1, ah0, al0);
        cvt8(a2, a3, ah1, al1);
        cvt8(b0, b1, bh0, bl0);
        cvt8(b2, b3, bh1, bl1);

        __syncthreads();   // prev chunk's LDS reads done before overwrite
        *(uint4*)(smem + AHI + wb0) = ah0;
        *(uint4*)(smem + AHI + wb1) = ah1;
        *(uint4*)(smem + ALO + wb0) = al0;
        *(uint4*)(smem + ALO + wb1) = al1;
        *(uint4*)(smem + BHI + wb0) = bh0;
        *(uint4*)(smem + BHI + wb1) = bh1;
        *(uint4*)(smem + BLO + wb0) = bl0;
        *(uint4*)(smem + BLO + wb1) = bl1;
        __syncthreads();

        // issue next-chunk loads AFTER the barrier: they fly under the MFMA
        // phase and are consumed (vmcnt-waited) only at next iter's cvt8.
        if (kc + 1 < NCHUNK) {
            const float* zn = zp + (kc + 1) * BK;
            const float* wn = wp + (kc + 1) * BK;
            a0 = *(const float4*)(zn + 0);  a1 = *(const float4*)(zn + 4);
            a2 = *(const float4*)(zn + 8);  a3 = *(const float4*)(zn + 12);
            b0 = *(const float4*)(wn + 0);  b1 = *(const float4*)(wn + 4);
            b2 = *(const float4*)(wn + 8);  b3 = *(const float4*)(wn + 12);
        }

        short8 ah[4], al[4], bh[4], bl[4];
#pragma unroll
        for (int m = 0; m < 4; ++m) {
            ah[m] = *(const short8*)(smem + AHI + aOff + m * 1024);
            al[m] = *(const short8*)(smem + ALO + aOff + m * 1024);
        }
#pragma unroll
        for (int n = 0; n < 4; ++n) {
            bh[n] = *(const short8*)(smem + BHI + bOff + n * 1024);
            bl[n] = *(const short8*)(smem + BLO + bOff + n * 1024);
        }
#pragma unroll
        for (int m = 0; m < 4; ++m)
#pragma unroll
            for (int n = 0; n < 4; ++n) {
                acc[m][n] = __builtin_amdgcn_mfma_f32_16x16x32_bf16(ah[m], bh[n], acc[m][n], 0, 0, 0);
                acc[m][n] = __builtin_amdgcn_mfma_f32_16x16x32_bf16(al[m], bh[n], acc[m][n], 0, 0, 0);
                acc[m][n] = __builtin_amdgcn_mfma_f32_16x16x32_bf16(ah[m], bl[n], acc[m][n], 0, 0, 0);
            }
    }

    // Epilogue: C/D layout (m89/m91-verified): row = m*16 + fq*4 + jj, col = n*16 + fr.
#pragma unroll
    for (int m = 0; m < 4; ++m) {
#pragma unroll
        for (int jj = 0; jj < 4; ++jj) {
            const int R = rowBase + wr * 64 + m * 16 + fq * 4 + jj;
            float* sp = scores + (size_t)R * (2 * K) + (size_t)h * K + colBase + wc * 64 + fr;
            unsigned long long best = 0ull, second = 0ull;
#pragma unroll
            for (int n = 0; n < 4; ++n) {
                const float v = acc[m][n][jj];
                sp[n * 16] = v;
                const int col = colBase + wc * 64 + n * 16 + fr;
                unsigned long long p =
                    ((unsigned long long)score_key(v) << 32) |
                    (unsigned long long)(0xFFFFFFFFu - (unsigned)col);
                if (p > best) { second = best; best = p; }
                else if (p > second) { second = p; }
            }
            // top-2 merge across the 16 fr-lanes (xor of tid bits 0..3 keeps fq)
#pragma unroll
            for (int w = 1; w < 16; w <<= 1) {
                unsigned long long ob = shfl_xor_u64(best, w);
                unsigned long long os = shfl_xor_u64(second, w);
                unsigned long long nb = best > ob ? best : ob;
                unsigned long long lose = best > ob ? ob : best;
                unsigned long long s2 = second > os ? second : os;
                best = nb;
                second = lose > s2 ? lose : s2;
            }
            if (fr == 0) {
                // lock-free global top-2: slot2 ends up exactly the global #2.
                unsigned long long* s1p = slot1 + (size_t)h * B + R;
                unsigned long long old = atomicMax(s1p, best);
                unsigned long long cand = old < best ? old : best;   // loser of slot1 duel
                if (second > cand) cand = second;
                atomicMax(slot2 + (size_t)h * B + R, cand);
            }
        }
    }
}

// Exact-fp32 rescore of the two candidates; writes final index.
__global__ __launch_bounds__(256) void fixup_kernel(
    const float* __restrict__ z, const float* __restrict__ Wa,
    const float* __restrict__ Wv, unsigned long long* __restrict__ ws)
{
    const int gid  = blockIdx.x * 4 + (threadIdx.x >> 6);   // 0..16383
    const int lane = threadIdx.x & 63;
    const int h    = gid >> 13;
    const int row  = gid & (B - 1);
    const unsigned long long* slot1 = ws;
    const unsigned long long* slot2 = ws + 2 * B;
    unsigned int* idxArr = (unsigned int*)(ws + 4 * B);

    const size_t sb = (size_t)h * B + row;
    const unsigned c1 = 0xFFFFFFFFu - (unsigned)(slot1[sb] & 0xFFFFFFFFull);
    const unsigned c2 = 0xFFFFFFFFu - (unsigned)(slot2[sb] & 0xFFFFFFFFull);
    const float* Wm = h ? Wv : Wa;
    const float* zr = z + (size_t)row * TWO_D + h * D;
    const float* w1 = Wm + (size_t)c1 * D;
    const float* w2 = Wm + (size_t)c2 * D;

    const int k0 = lane * 8;
    float4 za = *(const float4*)(zr + k0);
    float4 zb = *(const float4*)(zr + k0 + 4);
    float4 p  = *(const float4*)(w1 + k0);
    float4 q  = *(const float4*)(w1 + k0 + 4);
    float4 r  = *(const float4*)(w2 + k0);
    float4 s  = *(const float4*)(w2 + k0 + 4);

    float d1 = 0.f, d2 = 0.f;
    d1 = fmaf(za.x, p.x, d1); d1 = fmaf(za.y, p.y, d1);
    d1 = fmaf(za.z, p.z, d1); d1 = fmaf(za.w, p.w, d1);
    d1 = fmaf(zb.x, q.x, d1); d1 = fmaf(zb.y, q.y, d1);
    d1 = fmaf(zb.z, q.z, d1); d1 = fmaf(zb.w, q.w, d1);
    d2 = fmaf(za.x, r.x, d2); d2 = fmaf(za.y, r.y, d2);
    d2 = fmaf(za.z, r.z, d2); d2 = fmaf(za.w, r.w, d2);
    d2 = fmaf(zb.x, s.x, d2); d2 = fmaf(zb.y, s.y, d2);
    d2 = fmaf(zb.z, s.z, d2); d2 = fmaf(zb.w, s.w, d2);

#pragma unroll
    for (int m = 1; m < 64; m <<= 1) {
        d1 += __shfl_xor(d1, m, 64);
        d2 += __shfl_xor(d2, m, 64);
    }
    if (lane == 0)
        idxArr[sb] = (d2 > d1 || (d2 == d1 && c2 < c1)) ? c2 : c1;
}

__global__ __launch_bounds__(256) void gather_kernel(
    const float* __restrict__ Wa, const float* __restrict__ Wv,
    const unsigned long long* __restrict__ ws,
    float* __restrict__ out0, float* __restrict__ out1)
{
    const unsigned int* idxArr = (const unsigned int*)(ws + 4 * B);
    const int b = blockIdx.x;
    const int t = threadIdx.x;
    const unsigned ia = idxArr[b];
    const unsigned iv = idxArr[B + b];

    const float* src;
    size_t dst;
    if (t < 128) {
        src = Wa + (size_t)ia * D + t * 4;
        dst = (size_t)b * TWO_D + t * 4;
    } else {
        src = Wv + (size_t)iv * D + (t - 128) * 4;
        dst = (size_t)b * TWO_D + D + (t - 128) * 4;
    }
    float4 v = *(const float4*)src;
    *(float4*)(out0 + dst) = v;
    *(float4*)(out1 + dst) = v;
}

extern "C" void kernel_launch(void* const* d_in, const int* in_sizes, int n_in,
                              void* d_out, int out_size, void* d_ws, size_t ws_size,
                              hipStream_t stream) {
    const float* z  = (const float*)d_in[0];
    const float* Wa = (const float*)d_in[1];
    const float* Wv = (const float*)d_in[2];

    float* out0   = (float*)d_out;                       // z_q_x_st [B,2D]
    float* out1   = out0 + (size_t)B * TWO_D;            // z_q_x    [B,2D]
    float* scores = out1 + (size_t)B * TWO_D;            // indices  [B,2K]

    // ws layout: slot1 [2B] u64 | slot2 [2B] u64 | idx [2B] u32  (~320 KB)
    unsigned long long* ws = (unsigned long long*)d_ws;

    hipLaunchKernelGGL(init_ws_kernel, dim3((4 * B + 255) / 256), dim3(256), 0, stream, ws);
    hipLaunchKernelGGL(gemm_argmax_kernel, dim3(K / BN, B / BM, 2), dim3(256), 0, stream,
                       z, Wa, Wv, scores, ws, ws + 2 * (size_t)B);
    hipLaunchKernelGGL(fixup_kernel, dim3(2 * B / 4), dim3(256), 0, stream, z, Wa, Wv, ws);
    hipLaunchKernelGGL(gather_kernel, dim3(B), dim3(256), 0, stream, Wa, Wv, ws, out0, out1);
}

// Round 3
// 1228.569 us; speedup vs baseline: 1.0927x; 1.0927x over previous
//
#include <hip/hip_runtime.h>
#include <stdint.h>

// VQEmbedding: z[B,2D] fp32, W_a/W_v [K,D] fp32.
// out0 = z_q_st [B,2D], out1 = z_q [B,2D], out2 = scores [B,2K].
//
// Round 3: pre-split bf16 + global_load_lds GEMM.
//   split_kernel: one-time hi/lo bf16 decomposition of z and W into tiled,
//     chunk-swizzled arrays placed in the out0/out1 regions (33.55 MB each,
//     exact fit; gather overwrites them at the end — stream-ordered, safe).
//   gemm: m97-style 128x128 tile, BK=32, global_load_lds width-16 staging
//     (linear LDS dest, pre-swizzled global source), zero in-loop VALU cvt,
//     nontemporal score stores (don't evict operands from L3).
//   Numerics identical to round 2: hi*hi + lo*hi + hi*lo, fp32 accum,
//   exact top-2 + fp32 rescore fixup.

namespace {
constexpr int D     = 512;
constexpr int TWO_D = 1024;
constexpr int K     = 8192;
constexpr int B     = 8192;
constexpr int BM = 128, BN = 128, BK = 32;
constexpr int NCHUNK = D / BK;                    // 16 k-tiles
constexpr size_t LO_OFF = 8388608;                // elems: 2h*64*16*4096 (hi plane size)
}

typedef __attribute__((ext_vector_type(8))) short short8;
typedef __attribute__((ext_vector_type(4))) float f32x4;
typedef __attribute__((address_space(1))) const unsigned int GU32;
typedef __attribute__((address_space(3))) unsigned int LU32;

__device__ __forceinline__ void gload_lds16(const void* g, void* l) {
    __builtin_amdgcn_global_load_lds((GU32*)g, (LU32*)l, 16, 0, 0);
}

__device__ __forceinline__ unsigned int score_key(float s) {
    unsigned int u = __float_as_uint(s);
    return (u & 0x80000000u) ? ~u : (u | 0x80000000u);
}

__device__ __forceinline__ unsigned long long shfl_xor_u64(unsigned long long v, int m) {
    unsigned int hi = (unsigned int)(v >> 32), lo = (unsigned int)v;
    hi = __shfl_xor(hi, m, 64);
    lo = __shfl_xor(lo, m, 64);
    return ((unsigned long long)hi << 32) | lo;
}

// hi = truncated bf16 (packed pair), lo = RNE bf16 of remainder (packed pair).
__device__ __forceinline__ void cvt_pair(float x0, float x1, unsigned &hiw, unsigned &low) {
    unsigned u0 = __float_as_uint(x0), u1 = __float_as_uint(x1);
    hiw = (u0 >> 16) | (u1 & 0xFFFF0000u);
    float l0 = x0 - __uint_as_float(u0 & 0xFFFF0000u);
    float l1 = x1 - __uint_as_float(u1 & 0xFFFF0000u);
    asm("v_cvt_pk_bf16_f32 %0, %1, %2" : "=v"(low) : "v"(l0), "v"(l1));
}

__device__ __forceinline__ void cvt8(float4 a, float4 b, uint4 &h, uint4 &l) {
    cvt_pair(a.x, a.y, h.x, l.x);
    cvt_pair(a.z, a.w, h.y, l.y);
    cvt_pair(b.x, b.y, h.z, l.z);
    cvt_pair(b.z, b.w, h.w, l.w);
}

__global__ void init_ws_kernel(unsigned long long* __restrict__ ws) {
    int i = blockIdx.x * blockDim.x + threadIdx.x;
    if (i < 4 * B) ws[i] = 0ull;
}

// One block = one 128x32 tile of z or W. Writes hi/lo bf16 tiles, contiguous
// 4096-elem blocks, with the GEMM's read-swizzle pre-applied (chunk ^= row&3)
// so global_load_lds can copy linearly (rule: swizzle both sides or neither).
__global__ __launch_bounds__(256) void split_kernel(
    const float* __restrict__ z, const float* __restrict__ Wa,
    const float* __restrict__ Wv,
    uint16_t* __restrict__ zs,    // out0 region, 16,777,216 elems
    uint16_t* __restrict__ wsp)   // out1 region
{
    const int bid = blockIdx.x;            // 0..4095
    const bool isW = bid >= 2048;
    const int t  = bid & 2047;
    const int h  = t >> 10;
    const int rb = (t >> 4) & 63;          // row tile (z) or col tile (W)
    const int kc = t & 15;
    const int t2 = threadIdx.x;
    const int r  = t2 >> 1;                // row within tile
    const int kh = (t2 & 1) << 4;          // 0 / 16 k-elems

    const float* src;
    uint16_t* base;
    if (!isW) {
        src  = z + (size_t)(rb * 128 + r) * TWO_D + h * D + kc * 32 + kh;
        base = zs;
    } else {
        const float* W = h ? Wv : Wa;
        src  = W + (size_t)(rb * 128 + r) * D + kc * 32 + kh;
        base = wsp;
    }
    const size_t tbase = ((size_t)(h * 64 + rb) * 16 + kc) * 4096;

    float4 f0 = ((const float4*)src)[0], f1 = ((const float4*)src)[1];
    float4 f2 = ((const float4*)src)[2], f3 = ((const float4*)src)[3];
    uint4 hch[2], lch[2];
    cvt8(f0, f1, hch[0], lch[0]);
    cvt8(f2, f3, hch[1], lch[1]);

    const int swzr = r & 3;
    const int c0 = (t2 & 1) * 2;
#pragma unroll
    for (int j = 0; j < 2; ++j) {
        const int cpos = (c0 + j) ^ swzr;
        const size_t off = tbase + (size_t)r * 32 + cpos * 8;
        *(uint4*)(base + off)          = hch[j];
        *(uint4*)(base + LO_OFF + off) = lch[j];
    }
}

__global__ __launch_bounds__(256, 3) void gemm_argmax_kernel(
    const uint16_t* __restrict__ zs,          // split z (tiled)
    const uint16_t* __restrict__ wsp,         // split W (tiled)
    float* __restrict__ scores,               // [B, 2K]
    unsigned long long* __restrict__ slot1,   // [2][B]
    unsigned long long* __restrict__ slot2)   // [2][B]
{
    // 32 KB: Ahi | Alo | Bhi | Blo, each [128][32] bf16 (8 KB), chunk-swizzled.
    __shared__ __align__(16) uint16_t smem[16384];
    char* sm = (char*)smem;

    const int h = blockIdx.z;
    // bijective XCD chunked swizzle over the 64x64 tile grid
    int id = blockIdx.y * 64 + blockIdx.x;
    id = (id & 7) * 512 + (id >> 3);
    const int rb = id >> 6;
    const int cb = id & 63;
    const int rowBase = rb * BM;
    const int colBase = cb * BN;

    const int tid  = threadIdx.x;
    const int lane = tid & 63;
    const int wv   = tid >> 6;                 // 4 waves, 2x2
    const int wr   = wv >> 1, wc = wv & 1;
    const int fr   = lane & 15, fq = lane >> 4;

    const size_t zhib = (size_t)(h * 64 + rb) * 16 * 4096;   // + kc*4096
    const size_t whib = (size_t)(h * 64 + cb) * 16 * 4096;

    // frag read offsets (bytes); swizzle matches split_kernel's pre-swizzle
    const int swzc  = (fq ^ (fr & 3)) << 4;
    const int aByte = (wr * 64 + fr) * 64 + swzc;            // + m*1024
    const int bByte = (wc * 64 + fr) * 64 + swzc;            // + n*1024

    f32x4 acc[4][4];
#pragma unroll
    for (int m = 0; m < 4; ++m)
#pragma unroll
        for (int n = 0; n < 4; ++n) acc[m][n] = (f32x4){0.f, 0.f, 0.f, 0.f};

    auto STAGE = [&](int kc) {
        const uint16_t* za = zs  + zhib + (size_t)kc * 4096 + wv * 1024 + lane * 8;
        const uint16_t* wa = wsp + whib + (size_t)kc * 4096 + wv * 1024 + lane * 8;
        char* lb = sm + wv * 2048;      // wave-uniform LDS base (+lane*16 implicit)
        gload_lds16(za,                lb);
        gload_lds16(za + 512,          lb + 1024);
        gload_lds16(za + LO_OFF,       lb + 8192);
        gload_lds16(za + LO_OFF + 512, lb + 8192 + 1024);
        gload_lds16(wa,                lb + 16384);
        gload_lds16(wa + 512,          lb + 16384 + 1024);
        gload_lds16(wa + LO_OFF,       lb + 24576);
        gload_lds16(wa + LO_OFF + 512, lb + 24576 + 1024);
    };

    STAGE(0);
    __syncthreads();                    // drains vmcnt -> tile 0 resident

    for (int kc = 0; kc < NCHUNK; ++kc) {
        short8 ah[4], al[4], bh[4], bl[4];
#pragma unroll
        for (int m = 0; m < 4; ++m) {
            ah[m] = *(const short8*)(sm +         aByte + m * 1024);
            al[m] = *(const short8*)(sm + 8192  + aByte + m * 1024);
        }
#pragma unroll
        for (int n = 0; n < 4; ++n) {
            bh[n] = *(const short8*)(sm + 16384 + bByte + n * 1024);
            bl[n] = *(const short8*)(sm + 24576 + bByte + n * 1024);
        }
        __syncthreads();                // all waves' reads done before overwrite
        if (kc + 1 < NCHUNK) STAGE(kc + 1);   // loads fly under the MFMAs

#pragma unroll
        for (int m = 0; m < 4; ++m)
#pragma unroll
            for (int n = 0; n < 4; ++n) {
                acc[m][n] = __builtin_amdgcn_mfma_f32_16x16x32_bf16(ah[m], bh[n], acc[m][n], 0, 0, 0);
                acc[m][n] = __builtin_amdgcn_mfma_f32_16x16x32_bf16(al[m], bh[n], acc[m][n], 0, 0, 0);
                acc[m][n] = __builtin_amdgcn_mfma_f32_16x16x32_bf16(ah[m], bl[n], acc[m][n], 0, 0, 0);
            }
        __syncthreads();                // next tile staged (vmcnt drained)
    }

    // Epilogue: C/D layout row = m*16 + fq*4 + jj, col = n*16 + fr.
#pragma unroll
    for (int m = 0; m < 4; ++m) {
#pragma unroll
        for (int jj = 0; jj < 4; ++jj) {
            const int R = rowBase + wr * 64 + m * 16 + fq * 4 + jj;
            float* sp = scores + (size_t)R * (2 * K) + (size_t)h * K + colBase + wc * 64 + fr;
            unsigned long long best = 0ull, second = 0ull;
#pragma unroll
            for (int n = 0; n < 4; ++n) {
                const float v = acc[m][n][jj];
                __builtin_nontemporal_store(v, sp + n * 16);   // don't evict operands from L3
                const int col = colBase + wc * 64 + n * 16 + fr;
                unsigned long long p =
                    ((unsigned long long)score_key(v) << 32) |
                    (unsigned long long)(0xFFFFFFFFu - (unsigned)col);
                if (p > best) { second = best; best = p; }
                else if (p > second) { second = p; }
            }
#pragma unroll
            for (int w = 1; w < 16; w <<= 1) {
                unsigned long long ob = shfl_xor_u64(best, w);
                unsigned long long os = shfl_xor_u64(second, w);
                unsigned long long nb = best > ob ? best : ob;
                unsigned long long lose = best > ob ? ob : best;
                unsigned long long s2 = second > os ? second : os;
                best = nb;
                second = lose > s2 ? lose : s2;
            }
            if (fr == 0) {
                unsigned long long* s1p = slot1 + (size_t)h * B + R;
                unsigned long long old = atomicMax(s1p, best);
                unsigned long long cand = old < best ? old : best;
                if (second > cand) cand = second;
                atomicMax(slot2 + (size_t)h * B + R, cand);
            }
        }
    }
}

// Exact-fp32 rescore of the two candidates; writes final index.
__global__ __launch_bounds__(256) void fixup_kernel(
    const float* __restrict__ z, const float* __restrict__ Wa,
    const float* __restrict__ Wv, unsigned long long* __restrict__ ws)
{
    const int gid  = blockIdx.x * 4 + (threadIdx.x >> 6);
    const int lane = threadIdx.x & 63;
    const int h    = gid >> 13;
    const int row  = gid & (B - 1);
    const unsigned long long* slot1 = ws;
    const unsigned long long* slot2 = ws + 2 * B;
    unsigned int* idxArr = (unsigned int*)(ws + 4 * B);

    const size_t sb = (size_t)h * B + row;
    const unsigned c1 = 0xFFFFFFFFu - (unsigned)(slot1[sb] & 0xFFFFFFFFull);
    const unsigned c2 = 0xFFFFFFFFu - (unsigned)(slot2[sb] & 0xFFFFFFFFull);
    const float* Wm = h ? Wv : Wa;
    const float* zr = z + (size_t)row * TWO_D + h * D;
    const float* w1 = Wm + (size_t)c1 * D;
    const float* w2 = Wm + (size_t)c2 * D;

    const int k0 = lane * 8;
    float4 za = *(const float4*)(zr + k0);
    float4 zb = *(const float4*)(zr + k0 + 4);
    float4 p  = *(const float4*)(w1 + k0);
    float4 q  = *(const float4*)(w1 + k0 + 4);
    float4 r  = *(const float4*)(w2 + k0);
    float4 s  = *(const float4*)(w2 + k0 + 4);

    float d1 = 0.f, d2 = 0.f;
    d1 = fmaf(za.x, p.x, d1); d1 = fmaf(za.y, p.y, d1);
    d1 = fmaf(za.z, p.z, d1); d1 = fmaf(za.w, p.w, d1);
    d1 = fmaf(zb.x, q.x, d1); d1 = fmaf(zb.y, q.y, d1);
    d1 = fmaf(zb.z, q.z, d1); d1 = fmaf(zb.w, q.w, d1);
    d2 = fmaf(za.x, r.x, d2); d2 = fmaf(za.y, r.y, d2);
    d2 = fmaf(za.z, r.z, d2); d2 = fmaf(za.w, r.w, d2);
    d2 = fmaf(zb.x, s.x, d2); d2 = fmaf(zb.y, s.y, d2);
    d2 = fmaf(zb.z, s.z, d2); d2 = fmaf(zb.w, s.w, d2);

#pragma unroll
    for (int m = 1; m < 64; m <<= 1) {
        d1 += __shfl_xor(d1, m, 64);
        d2 += __shfl_xor(d2, m, 64);
    }
    if (lane == 0)
        idxArr[sb] = (d2 > d1 || (d2 == d1 && c2 < c1)) ? c2 : c1;
}

__global__ __launch_bounds__(256) void gather_kernel(
    const float* __restrict__ Wa, const float* __restrict__ Wv,
    const unsigned long long* __restrict__ ws,
    float* __restrict__ out0, float* __restrict__ out1)
{
    const unsigned int* idxArr = (const unsigned int*)(ws + 4 * B);
    const int b = blockIdx.x;
    const int t = threadIdx.x;
    const unsigned ia = idxArr[b];
    const unsigned iv = idxArr[B + b];

    const float* src;
    size_t dst;
    if (t < 128) {
        src = Wa + (size_t)ia * D + t * 4;
        dst = (size_t)b * TWO_D + t * 4;
    } else {
        src = Wv + (size_t)iv * D + (t - 128) * 4;
        dst = (size_t)b * TWO_D + D + (t - 128) * 4;
    }
    float4 v = *(const float4*)src;
    *(float4*)(out0 + dst) = v;
    *(float4*)(out1 + dst) = v;
}

extern "C" void kernel_launch(void* const* d_in, const int* in_sizes, int n_in,
                              void* d_out, int out_size, void* d_ws, size_t ws_size,
                              hipStream_t stream) {
    const float* z  = (const float*)d_in[0];
    const float* Wa = (const float*)d_in[1];
    const float* Wv = (const float*)d_in[2];

    float* out0   = (float*)d_out;                       // z_q_x_st [B,2D]
    float* out1   = out0 + (size_t)B * TWO_D;            // z_q_x    [B,2D]
    float* scores = out1 + (size_t)B * TWO_D;            // indices  [B,2K]

    // out0/out1 regions double as split-operand scratch (33.55 MB each, exact
    // fit); they are consumed by gemm, then overwritten by gather. Stream-
    // ordered -> no hazard.
    uint16_t* zsplit = (uint16_t*)out0;
    uint16_t* wsplit = (uint16_t*)out1;

    unsigned long long* ws = (unsigned long long*)d_ws;  // slot1|slot2|idx, 384 KB

    hipLaunchKernelGGL(init_ws_kernel, dim3((4 * B + 255) / 256), dim3(256), 0, stream, ws);
    hipLaunchKernelGGL(split_kernel, dim3(4096), dim3(256), 0, stream,
                       z, Wa, Wv, zsplit, wsplit);
    hipLaunchKernelGGL(gemm_argmax_kernel, dim3(K / BN, B / BM, 2), dim3(256), 0, stream,
                       zsplit, wsplit, scores, ws, ws + 2 * (size_t)B);
    hipLaunchKernelGGL(fixup_kernel, dim3(2 * B / 4), dim3(256), 0, stream, z, Wa, Wv, ws);
    hipLaunchKernelGGL(gather_kernel, dim3(B), dim3(256), 0, stream, Wa, Wv, ws, out0, out1);
}